// Round 1
// baseline (211.148 us; speedup 1.0000x reference)
//
#include <hip/hip_runtime.h>
#include <math.h>

#define NN 200000
#define DD 64
#define BB 4096
#define KK 128
#define WW 20
#define HH 128

// ---------------- Kernel 1: per-target encodings + neighbor attention agg + hist agg ----------------
// grid = B blocks, 256 threads (4 waves). Wave w handles neighbors [w*32, w*32+32).
// Writes feat4[b][256] = [hist_agg(128) | tgt_feat(64) | neigh_agg(64)] to workspace.
__global__ __launch_bounds__(256) void k1_encode(
    const float* __restrict__ adj_time, const float* __restrict__ gc,
    const float* __restrict__ cur_time, const float* __restrict__ neigh_mask,
    const float* __restrict__ hist_feat, const float* __restrict__ hist_time,
    const float* __restrict__ t2v_w, const float* __restrict__ t2v_b,
    const float* __restrict__ node_w, const float* __restrict__ node_b,
    const float* __restrict__ att_w, const float* __restrict__ att_b,
    const int* __restrict__ targets, const int* __restrict__ neigh_idx,
    float* __restrict__ feat4)
{
    const int b    = blockIdx.x;
    const int tid  = threadIdx.x;
    const int lane = tid & 63;
    const int wid  = tid >> 6;

    __shared__ float hws[WW];
    __shared__ float hpart[128];
    __shared__ float aggp[4][64];

    const float t = cur_time[0];

    // ---- history decay weights ----
    if (tid < WW) {
        float ht = hist_time[b * WW + tid];
        hws[tid] = 1.0f / (2.0f * (1.0f + (t - ht)));
    }
    __syncthreads();

    // ---- history aggregation: thread = (half = tid>>7, d = tid&127), each sums 10 w's ----
    {
        int half = tid >> 7;
        int d    = tid & 127;
        const float* hf = hist_feat + (size_t)b * WW * 128 + d;
        float s = 0.f;
#pragma unroll
        for (int w = 0; w < 10; ++w) {
            int ww = half * 10 + w;
            s += hws[ww] * hf[ww * 128];
        }
        if (half) hpart[d] = s;
        __syncthreads();
        if (!half) feat4[b * 256 + d] = s + hpart[d];
    }

    // ---- per-lane parameters (lane = dim) ----
    const float wv  = t2v_w[lane];
    const float bv  = t2v_b[lane];
    const float nw  = node_w[lane];
    const float nb  = node_b[lane];
    const float aw1 = att_w[lane];
    const float aw2 = att_w[64 + lane];
    const float ab  = att_b[0];

    // ---- target encoding (computed redundantly in every wave; avoids extra barrier) ----
    const int tgt = targets[b];
    float st;   // dot(tgt_featN, att_w[:64]) -- broadcast across lanes
    {
        float dt = fabsf(t - adj_time[tgt]);
        float g  = gc[tgt];
        float ph = wv * dt + bv;
        float tv = (lane == 0) ? ph : __cosf(ph);
        float f  = fmaxf(tv + g * nw + nb, 0.f);
        float ss = f * f;
#pragma unroll
        for (int off = 32; off; off >>= 1) ss += __shfl_xor(ss, off, 64);
        float inv = 1.0f / fmaxf(sqrtf(ss), 1e-12f);
        float tfn = f * inv;
        float sd  = tfn * aw1;
#pragma unroll
        for (int off = 32; off; off >>= 1) sd += __shfl_xor(sd, off, 64);
        st = sd;
        if (wid == 0) feat4[b * 256 + 128 + lane] = tfn;
    }

    // ---- neighbor pre-gather (lanes 0..31 hold one neighbor's scalars each) ----
    float at_l = 0.f, gc_l = 0.f, m_l = 0.f, ts_l = 0.f;
    if (lane < 32) {
        int k   = wid * 32 + lane;
        int idx = neigh_idx[b * KK + k];
        at_l = adj_time[idx];
        gc_l = gc[idx];
        m_l  = neigh_mask[b * KK + k];
        ts_l = 1.0f / (2.0f * __logf(2.71828182845904523536f + (t - at_l)));
    }

    // ---- neighbor loop: one neighbor per iteration, 64 lanes = 64 dims ----
    float acc = 0.f;
#pragma unroll 4
    for (int j = 0; j < 32; ++j) {
        float a  = __shfl(at_l, j, 64);
        float g  = __shfl(gc_l, j, 64);
        float m  = __shfl(m_l, j, 64);
        float ts = __shfl(ts_l, j, 64);

        float dt = fabsf(t - a);
        float ph = wv * dt + bv;
        float tv = (lane == 0) ? ph : __cosf(ph);
        float f  = fmaxf(tv + g * nw + nb, 0.f);

        float s2 = f * f;       // for L2 norm
        float sd = f * aw2;     // for attention dot
#pragma unroll
        for (int off = 32; off; off >>= 1) {
            s2 += __shfl_xor(s2, off, 64);
            sd += __shfl_xor(sd, off, 64);
        }
        float invn = 1.0f / fmaxf(sqrtf(s2), 1e-12f);
        float fn = f * invn;
        float sn = sd * invn;

        float sc = ts + st + sn + ab;
        sc = (sc > 0.f) ? sc : 0.01f * sc;   // leaky_relu(0.01)
        sc *= m;
        acc += sc * fn;
    }

    aggp[wid][lane] = acc;
    __syncthreads();
    if (tid < 64) {
        float s = aggp[0][tid] + aggp[1][tid] + aggp[2][tid] + aggp[3][tid];
        feat4[b * 256 + 192 + tid] = s;
    }
}

// ---------------- Kernel 2: out = relu(feat4 @ weight^T) ----------------
// grid = B/8 blocks, 256 threads. Thread = (h = tid&127, g = tid>>7); owns 4 targets.
__global__ __launch_bounds__(256) void k2_gemm(
    const float* __restrict__ feat4, const float* __restrict__ weight,
    float* __restrict__ out)
{
    const int b0  = blockIdx.x * 8;
    const int tid = threadIdx.x;

    __shared__ float tile[8 * 256];
    {
        const float4* src = (const float4*)(feat4 + (size_t)b0 * 256);
        float4* dst = (float4*)tile;
        dst[tid]       = src[tid];
        dst[tid + 256] = src[tid + 256];
    }
    __syncthreads();

    const int h = tid & 127;
    const int g = tid >> 7;

    float acc0 = 0.f, acc1 = 0.f, acc2 = 0.f, acc3 = 0.f;
    const float4* wrow = (const float4*)(weight + (size_t)h * 256);
    const float* tb = tile + (g * 4) * 256;

#pragma unroll 8
    for (int j4 = 0; j4 < 64; ++j4) {
        float4 w4 = wrow[j4];
        float4 f0 = ((const float4*)(tb + 0 * 256))[j4];
        float4 f1 = ((const float4*)(tb + 1 * 256))[j4];
        float4 f2 = ((const float4*)(tb + 2 * 256))[j4];
        float4 f3 = ((const float4*)(tb + 3 * 256))[j4];
        acc0 += w4.x * f0.x + w4.y * f0.y + w4.z * f0.z + w4.w * f0.w;
        acc1 += w4.x * f1.x + w4.y * f1.y + w4.z * f1.z + w4.w * f1.w;
        acc2 += w4.x * f2.x + w4.y * f2.y + w4.z * f2.z + w4.w * f2.w;
        acc3 += w4.x * f3.x + w4.y * f3.y + w4.z * f3.z + w4.w * f3.w;
    }

    out[(size_t)(b0 + g * 4 + 0) * 128 + h] = fmaxf(acc0, 0.f);
    out[(size_t)(b0 + g * 4 + 1) * 128 + h] = fmaxf(acc1, 0.f);
    out[(size_t)(b0 + g * 4 + 2) * 128 + h] = fmaxf(acc2, 0.f);
    out[(size_t)(b0 + g * 4 + 3) * 128 + h] = fmaxf(acc3, 0.f);
}

extern "C" void kernel_launch(void* const* d_in, const int* in_sizes, int n_in,
                              void* d_out, int out_size, void* d_ws, size_t ws_size,
                              hipStream_t stream) {
    const float* adj_time  = (const float*)d_in[0];
    const float* gc        = (const float*)d_in[1];
    const float* cur_time  = (const float*)d_in[2];
    const float* neigh_mask= (const float*)d_in[3];
    const float* hist_feat = (const float*)d_in[4];
    const float* hist_time = (const float*)d_in[5];
    const float* t2v_w     = (const float*)d_in[6];
    const float* t2v_b     = (const float*)d_in[7];
    const float* node_w    = (const float*)d_in[8];
    const float* node_b    = (const float*)d_in[9];
    const float* att_w     = (const float*)d_in[10];
    const float* att_b     = (const float*)d_in[11];
    const float* weight    = (const float*)d_in[12];
    const int*   targets   = (const int*)d_in[13];
    const int*   neigh_idx = (const int*)d_in[14];

    float* out   = (float*)d_out;
    float* feat4 = (float*)d_ws;   // B*256 floats = 4 MB

    k1_encode<<<BB, 256, 0, stream>>>(adj_time, gc, cur_time, neigh_mask,
                                      hist_feat, hist_time, t2v_w, t2v_b,
                                      node_w, node_b, att_w, att_b,
                                      targets, neigh_idx, feat4);

    k2_gemm<<<BB / 8, 256, 0, stream>>>(feat4, weight, out);
}

// Round 2
// 140.925 us; speedup vs baseline: 1.4983x; 1.4983x over previous
//
#include <hip/hip_runtime.h>
#include <math.h>

#define NN 200000
#define DD 64
#define BB 4096
#define KK 128
#define WW 20
#define HH 128

__device__ __forceinline__ float fast_rcp(float x) { return __builtin_amdgcn_rcpf(x); }
__device__ __forceinline__ float fast_rsq(float x) { return __builtin_amdgcn_rsqf(x); }

// ---------------- Kernel 1 ----------------
// One block per target, 256 threads.
// Phase 1: thread = (k = tid&127, half = tid>>7); each computes 32 dims of neighbor k
//          fully in-lane (no cross-lane reduction), stores raw feat to LDS (stride 65).
// Phase 2: lane = dim; wave w accumulates 32 neighbors with plain FMAs.
// feat4[b][256] = [hist_agg(128) | tgt_feat(64) | neigh_agg(64)]
__global__ __launch_bounds__(256) void k1_encode(
    const float* __restrict__ adj_time, const float* __restrict__ gc,
    const float* __restrict__ cur_time, const float* __restrict__ neigh_mask,
    const float* __restrict__ hist_feat, const float* __restrict__ hist_time,
    const float* __restrict__ t2v_w, const float* __restrict__ t2v_b,
    const float* __restrict__ node_w, const float* __restrict__ node_b,
    const float* __restrict__ att_w, const float* __restrict__ att_b,
    const int* __restrict__ targets, const int* __restrict__ neigh_idx,
    float* __restrict__ feat4)
{
    const int b    = blockIdx.x;
    const int tid  = threadIdx.x;
    const int lane = tid & 63;
    const int wid  = tid >> 6;

    __shared__ float4 p4[64];          // {t2v_w, t2v_b, node_w, node_b} per dim
    __shared__ float  aw2s[64];        // att_w[64+d]
    __shared__ float  hws[WW];
    __shared__ float  hpart[128];
    __shared__ float  fnL[128 * 65];   // raw neighbor features, stride-65 (conflict-free)
    __shared__ float  s2h[128];
    __shared__ float  sdh[128];
    __shared__ float  wk[128];         // per-neighbor weight = score*mask*invnorm
    __shared__ float  aggp[4][64];
    __shared__ float  stL;             // dot(tgt_featN, att_w[:64])

    const float t = cur_time[0];

    // ---- stage params ----
    if (tid < 64) {
        p4[tid]   = make_float4(t2v_w[tid], t2v_b[tid], node_w[tid], node_b[tid]);
        aw2s[tid] = att_w[64 + tid];
    }
    if (tid < WW) {
        hws[tid] = fast_rcp(2.0f * (1.0f + (t - hist_time[b * WW + tid])));
    }
    __syncthreads();   // A: params + hws ready

    // ---- history partial sums (uses hws) ----
    float hsum;
    {
        int half = tid >> 7;
        int d    = tid & 127;
        const float* hf = hist_feat + (size_t)b * WW * 128 + d;
        float s = 0.f;
#pragma unroll
        for (int w = 0; w < 10; ++w) {
            int ww = half * 10 + w;
            s = fmaf(hws[ww], hf[ww * 128], s);
        }
        if (half) hpart[d] = s;
        hsum = s;
    }

    // ---- target encoding (wave 0 only, overlaps with other waves' gathers) ----
    if (wid == 0) {
        int   tg  = targets[b];
        float dtT = fabsf(t - adj_time[tg]);
        float gT  = gc[tg];
        float4 p  = p4[lane];
        float ph  = fmaf(p.x, dtT, p.y);
        float tv  = (lane == 0) ? ph : __cosf(ph);
        float f   = fmaxf(tv + fmaf(gT, p.z, p.w), 0.f);
        float ss  = f * f;
#pragma unroll
        for (int off = 32; off; off >>= 1) ss += __shfl_xor(ss, off, 64);
        float invn = fast_rsq(fmaxf(ss, 1e-24f));
        float tfn  = f * invn;
        float sdt  = tfn * att_w[lane];
#pragma unroll
        for (int off = 32; off; off >>= 1) sdt += __shfl_xor(sdt, off, 64);
        if (lane == 0) stL = sdt;
        feat4[b * 256 + 128 + lane] = tfn;
    }

    // ---- phase 1: per-neighbor, in-lane ----
    const int   k    = tid & 127;
    const int   half = tid >> 7;
    const int   idx  = neigh_idx[b * KK + k];
    const float at   = adj_time[idx];
    const float g    = gc[idx];
    const float dtN  = fabsf(t - at);

    __syncthreads();   // B: hpart + stL written

    // history combine (half 0 writes)
    if (!half) {
        int d = tid & 127;
        feat4[b * 256 + d] = hsum + hpart[d];
    }

    float s2 = 0.f, sd = 0.f;
    {
        float* fnRow = fnL + k * 65 + half * 32;
#pragma unroll
        for (int dd = 0; dd < 32; ++dd) {
            int    d  = half * 32 + dd;
            float4 p  = p4[d];
            float  ph = fmaf(p.x, dtN, p.y);
            float  cv = __cosf(ph);
            float  tv = (d == 0) ? ph : cv;
            float  f  = fmaxf(tv + fmaf(g, p.z, p.w), 0.f);
            fnRow[dd] = f;
            s2 = fmaf(f, f, s2);
            sd = fmaf(f, aw2s[d], sd);
        }
    }
    if (half) { s2h[k] = s2; sdh[k] = sd; }
    __syncthreads();   // C: fnL + half-1 partials ready

    if (!half) {
        s2 += s2h[k];
        sd += sdh[k];
        float invn = fast_rsq(fmaxf(s2, 1e-24f));
        float ts   = fast_rcp(2.0f * __logf(2.71828182845904523536f + (t - at)));
        float m    = neigh_mask[b * KK + k];
        float sc   = ts + stL + sd * invn + att_b[0];
        sc = (sc > 0.f) ? sc : 0.01f * sc;     // leaky_relu(0.01)
        wk[k] = sc * m * invn;
    }
    __syncthreads();   // D: wk ready

    // ---- phase 2: lane = dim, wave wid handles neighbors [wid*32, wid*32+32) ----
    float acc = 0.f;
    {
        const int k0 = wid * 32;
#pragma unroll
        for (int j = 0; j < 32; ++j) {
            acc = fmaf(wk[k0 + j], fnL[(k0 + j) * 65 + lane], acc);
        }
    }
    aggp[wid][lane] = acc;
    __syncthreads();   // E
    if (tid < 64) {
        feat4[b * 256 + 192 + tid] =
            aggp[0][tid] + aggp[1][tid] + aggp[2][tid] + aggp[3][tid];
    }
}

// ---------------- Kernel 2: out = relu(feat4 @ weight^T) ----------------
// 512 blocks x 256 thr; block handles 8 targets. Weight staged chunk-wise in LDS
// (coalesced global loads); compute reads are broadcast / conflict-free.
__global__ __launch_bounds__(256) void k2_gemm(
    const float* __restrict__ feat4, const float* __restrict__ weight,
    float* __restrict__ out)
{
    const int b0  = blockIdx.x * 8;
    const int tid = threadIdx.x;

    __shared__ float tile[8 * 256];      // feat rows
    __shared__ float wl[128 * 33];       // W chunk [128 h][32 j], pad 33

    {
        const float4* src = (const float4*)(feat4 + (size_t)b0 * 256);
        float4* dst = (float4*)tile;
        dst[tid]       = src[tid];
        dst[tid + 256] = src[tid + 256];
    }

    const int h = tid & 127;
    const int g = tid >> 7;
    const float* tb = tile + (g * 4) * 256;

    float acc0 = 0.f, acc1 = 0.f, acc2 = 0.f, acc3 = 0.f;

    for (int c = 0; c < 8; ++c) {
        __syncthreads();   // protects wl overwrite (covers tile load on c=0)
        // stage W[:, c*32 .. c*32+32): 4096 elems, 16 per thread, coalesced
#pragma unroll
        for (int i = 0; i < 16; ++i) {
            int l  = i * 256 + tid;
            int hh = l >> 5;
            int jj = l & 31;
            wl[hh * 33 + jj] = weight[hh * 256 + c * 32 + jj];
        }
        __syncthreads();

#pragma unroll
        for (int jj = 0; jj < 32; jj += 4) {
            float w0 = wl[h * 33 + jj + 0];
            float w1 = wl[h * 33 + jj + 1];
            float w2 = wl[h * 33 + jj + 2];
            float w3 = wl[h * 33 + jj + 3];
            float4 f0 = *(const float4*)(tb + 0 * 256 + c * 32 + jj);
            float4 f1 = *(const float4*)(tb + 1 * 256 + c * 32 + jj);
            float4 f2 = *(const float4*)(tb + 2 * 256 + c * 32 + jj);
            float4 f3 = *(const float4*)(tb + 3 * 256 + c * 32 + jj);
            acc0 += w0 * f0.x + w1 * f0.y + w2 * f0.z + w3 * f0.w;
            acc1 += w0 * f1.x + w1 * f1.y + w2 * f1.z + w3 * f1.w;
            acc2 += w0 * f2.x + w1 * f2.y + w2 * f2.z + w3 * f2.w;
            acc3 += w0 * f3.x + w1 * f3.y + w2 * f3.z + w3 * f3.w;
        }
    }

    out[(size_t)(b0 + g * 4 + 0) * 128 + h] = fmaxf(acc0, 0.f);
    out[(size_t)(b0 + g * 4 + 1) * 128 + h] = fmaxf(acc1, 0.f);
    out[(size_t)(b0 + g * 4 + 2) * 128 + h] = fmaxf(acc2, 0.f);
    out[(size_t)(b0 + g * 4 + 3) * 128 + h] = fmaxf(acc3, 0.f);
}

extern "C" void kernel_launch(void* const* d_in, const int* in_sizes, int n_in,
                              void* d_out, int out_size, void* d_ws, size_t ws_size,
                              hipStream_t stream) {
    const float* adj_time  = (const float*)d_in[0];
    const float* gc        = (const float*)d_in[1];
    const float* cur_time  = (const float*)d_in[2];
    const float* neigh_mask= (const float*)d_in[3];
    const float* hist_feat = (const float*)d_in[4];
    const float* hist_time = (const float*)d_in[5];
    const float* t2v_w     = (const float*)d_in[6];
    const float* t2v_b     = (const float*)d_in[7];
    const float* node_w    = (const float*)d_in[8];
    const float* node_b    = (const float*)d_in[9];
    const float* att_w     = (const float*)d_in[10];
    const float* att_b     = (const float*)d_in[11];
    const float* weight    = (const float*)d_in[12];
    const int*   targets   = (const int*)d_in[13];
    const int*   neigh_idx = (const int*)d_in[14];

    float* out   = (float*)d_out;
    float* feat4 = (float*)d_ws;   // B*256 floats = 4 MB

    k1_encode<<<BB, 256, 0, stream>>>(adj_time, gc, cur_time, neigh_mask,
                                      hist_feat, hist_time, t2v_w, t2v_b,
                                      node_w, node_b, att_w, att_b,
                                      targets, neigh_idx, feat4);

    k2_gemm<<<BB / 8, 256, 0, stream>>>(feat4, weight, out);
}

// Round 3
// 137.011 us; speedup vs baseline: 1.5411x; 1.0286x over previous
//
#include <hip/hip_runtime.h>
#include <math.h>

#define NN 200000
#define DD 64
#define BB 4096
#define KK 128
#define WW 20
#define HH 128

__device__ __forceinline__ float fast_rcp(float x) { return __builtin_amdgcn_rcpf(x); }
__device__ __forceinline__ float fast_rsq(float x) { return __builtin_amdgcn_rsqf(x); }

// ---------------- Kernel 1 ----------------
// One block per target, 256 threads, ~6KB LDS (8 blocks/CU resident).
// Pre-A : waves 0/1 gather neighbor scalars (once), wave 2 history weights,
//         wave 3 target encoding (shuffle-reduced).
// Phase1: thread=(k=tid&127, half=tid>>7) computes 32 dims in-lane; per-dim
//         params via wave-uniform s_loads (readfirstlane). No feature store.
// Phase2: lane=dim, wave=32 neighbors; RECOMPUTES feature (cos is cheap),
//         accumulates wk[k]*f[k][lane] with plain FMAs.
// feat4[b][256] = [hist_agg(128) | tgt_feat(64) | neigh_agg(64)]
__global__ __launch_bounds__(256) void k1_encode(
    const float* __restrict__ adj_time, const float* __restrict__ gc,
    const float* __restrict__ cur_time, const float* __restrict__ neigh_mask,
    const float* __restrict__ hist_feat, const float* __restrict__ hist_time,
    const float* __restrict__ t2v_w, const float* __restrict__ t2v_b,
    const float* __restrict__ node_w, const float* __restrict__ node_b,
    const float* __restrict__ att_w, const float* __restrict__ att_b,
    const int* __restrict__ targets, const int* __restrict__ neigh_idx,
    float* __restrict__ feat4)
{
    const int b    = blockIdx.x;
    const int tid  = threadIdx.x;
    const int lane = tid & 63;
    const int wid  = tid >> 6;
    const int k    = tid & 127;
    const int half = tid >> 7;

    __shared__ float  hws[WW];
    __shared__ float  hpart[128];
    __shared__ float4 dtg[128];      // {dt, g, wk, -} per neighbor
    __shared__ float2 sp[2][128];    // {s2, sd} partials per half
    __shared__ float  aggp[4][64];
    __shared__ float  stL;

    const float t = cur_time[0];

    // ---- pre-A: gathers (waves 0,1), hist weights (wave 2), target enc (wave 3) ----
    float ts_k = 0.f, m_k = 0.f;
    if (tid < 128) {
        int   idx = neigh_idx[b * KK + k];
        m_k       = neigh_mask[b * KK + k];
        float at  = adj_time[idx];
        float g   = gc[idx];
        float dt  = fabsf(t - at);
        dtg[k]    = make_float4(dt, g, 0.f, 0.f);
        ts_k      = fast_rcp(2.0f * __logf(2.71828182845904523536f + (t - at)));
    } else if (wid == 2) {
        if (lane < WW)
            hws[lane] = fast_rcp(2.0f * (1.0f + (t - hist_time[b * WW + lane])));
    } else { // wave 3: target encoding
        int   tg  = targets[b];
        float dtT = fabsf(t - adj_time[tg]);
        float gT  = gc[tg];
        float pw  = t2v_w[lane], pb = t2v_b[lane];
        float nw  = node_w[lane], nb2 = node_b[lane];
        float ph  = fmaf(pw, dtT, pb);
        float tv  = (lane == 0) ? ph : __cosf(ph);
        float f   = fmaxf(tv + fmaf(gT, nw, nb2), 0.f);
        float ss  = f * f;
#pragma unroll
        for (int off = 32; off; off >>= 1) ss += __shfl_xor(ss, off, 64);
        float invn = fast_rsq(fmaxf(ss, 1e-24f));
        float tfn  = f * invn;
        float sdt  = tfn * att_w[lane];
#pragma unroll
        for (int off = 32; off; off >>= 1) sdt += __shfl_xor(sdt, off, 64);
        if (lane == 0) stL = sdt;
        feat4[b * 256 + 128 + lane] = tfn;
    }
    __syncthreads();   // A: dtg, hws, stL ready

    // ---- history loads into registers (HBM latency overlaps phase-1 VALU) ----
    float hv[10];
    {
        const float* hf = hist_feat + (size_t)b * WW * 128 + (tid & 127);
#pragma unroll
        for (int w = 0; w < 10; ++w) hv[w] = hf[(half * 10 + w) * 128];
    }

    // ---- phase 1: per-(k,half) 32 dims in-lane; params via s_loads ----
    {
        const int du0 = __builtin_amdgcn_readfirstlane(half * 32);
        float4 dg = dtg[k];
        float  dt = dg.x, g = dg.y;
        float  s2 = 0.f, sd = 0.f;
#pragma unroll
        for (int dd = 0; dd < 32; ++dd) {
            int   d   = du0 + dd;               // wave-uniform -> scalar loads
            float pw  = t2v_w[d], pb = t2v_b[d];
            float nw  = node_w[d], nb2 = node_b[d];
            float a2  = att_w[64 + d];
            float ph  = fmaf(pw, dt, pb);
            float cv  = __cosf(ph);
            float tv  = (d == 0) ? ph : cv;
            float f   = fmaxf(tv + fmaf(g, nw, nb2), 0.f);
            s2 = fmaf(f, f, s2);
            sd = fmaf(f, a2, sd);
        }
        sp[half][k] = make_float2(s2, sd);
    }

    // ---- history partial combine (hws already read; hv in regs) ----
    float hsum = 0.f;
#pragma unroll
    for (int w = 0; w < 10; ++w) hsum = fmaf(hws[half * 10 + w], hv[w], hsum);
    if (half) hpart[tid & 127] = hsum;

    __syncthreads();   // B: sp + hpart + stL consumed next

    if (!half) {
        // history final
        feat4[b * 256 + (tid & 127)] = hsum + hpart[tid & 127];
        // neighbor weight wk[k]
        float2 a0 = sp[0][k], a1 = sp[1][k];
        float  s2 = a0.x + a1.x;
        float  sd = a0.y + a1.y;
        float  invn = fast_rsq(fmaxf(s2, 1e-24f));
        float  sc = ts_k + stL + sd * invn + att_b[0];
        sc = (sc > 0.f) ? sc : 0.01f * sc;     // leaky_relu(0.01)
        dtg[k].z = sc * m_k * invn;
    }
    __syncthreads();   // C: wk ready

    // ---- phase 2: lane=dim, wave wid recomputes 32 neighbors, FMA-accumulate ----
    {
        float pw  = t2v_w[lane], pb = t2v_b[lane];
        float nw  = node_w[lane], nb2 = node_b[lane];
        float acc = 0.f;
        const int k0 = wid * 32;
#pragma unroll 8
        for (int j = 0; j < 32; ++j) {
            float4 dg = dtg[k0 + j];            // uniform addr -> broadcast
            float  ph = fmaf(pw, dg.x, pb);
            float  cv = __cosf(ph);
            float  tv = (lane == 0) ? ph : cv;
            float  f  = fmaxf(tv + fmaf(dg.y, nw, nb2), 0.f);
            acc = fmaf(dg.z, f, acc);
        }
        aggp[wid][lane] = acc;
    }
    __syncthreads();   // D

    if (tid < 64) {
        feat4[b * 256 + 192 + tid] =
            aggp[0][tid] + aggp[1][tid] + aggp[2][tid] + aggp[3][tid];
    }
}

// ---------------- Kernel 2: out = relu(feat4 @ weight^T) ----------------
// (unchanged from R2 to isolate k1's effect)
__global__ __launch_bounds__(256) void k2_gemm(
    const float* __restrict__ feat4, const float* __restrict__ weight,
    float* __restrict__ out)
{
    const int b0  = blockIdx.x * 8;
    const int tid = threadIdx.x;

    __shared__ float tile[8 * 256];      // feat rows
    __shared__ float wl[128 * 33];       // W chunk [128 h][32 j], pad 33

    {
        const float4* src = (const float4*)(feat4 + (size_t)b0 * 256);
        float4* dst = (float4*)tile;
        dst[tid]       = src[tid];
        dst[tid + 256] = src[tid + 256];
    }

    const int h = tid & 127;
    const int g = tid >> 7;
    const float* tb = tile + (g * 4) * 256;

    float acc0 = 0.f, acc1 = 0.f, acc2 = 0.f, acc3 = 0.f;

    for (int c = 0; c < 8; ++c) {
        __syncthreads();   // protects wl overwrite (covers tile load on c=0)
#pragma unroll
        for (int i = 0; i < 16; ++i) {
            int l  = i * 256 + tid;
            int hh = l >> 5;
            int jj = l & 31;
            wl[hh * 33 + jj] = weight[hh * 256 + c * 32 + jj];
        }
        __syncthreads();

#pragma unroll
        for (int jj = 0; jj < 32; jj += 4) {
            float w0 = wl[h * 33 + jj + 0];
            float w1 = wl[h * 33 + jj + 1];
            float w2 = wl[h * 33 + jj + 2];
            float w3 = wl[h * 33 + jj + 3];
            float4 f0 = *(const float4*)(tb + 0 * 256 + c * 32 + jj);
            float4 f1 = *(const float4*)(tb + 1 * 256 + c * 32 + jj);
            float4 f2 = *(const float4*)(tb + 2 * 256 + c * 32 + jj);
            float4 f3 = *(const float4*)(tb + 3 * 256 + c * 32 + jj);
            acc0 += w0 * f0.x + w1 * f0.y + w2 * f0.z + w3 * f0.w;
            acc1 += w0 * f1.x + w1 * f1.y + w2 * f1.z + w3 * f1.w;
            acc2 += w0 * f2.x + w1 * f2.y + w2 * f2.z + w3 * f2.w;
            acc3 += w0 * f3.x + w1 * f3.y + w2 * f3.z + w3 * f3.w;
        }
    }

    out[(size_t)(b0 + g * 4 + 0) * 128 + h] = fmaxf(acc0, 0.f);
    out[(size_t)(b0 + g * 4 + 1) * 128 + h] = fmaxf(acc1, 0.f);
    out[(size_t)(b0 + g * 4 + 2) * 128 + h] = fmaxf(acc2, 0.f);
    out[(size_t)(b0 + g * 4 + 3) * 128 + h] = fmaxf(acc3, 0.f);
}

extern "C" void kernel_launch(void* const* d_in, const int* in_sizes, int n_in,
                              void* d_out, int out_size, void* d_ws, size_t ws_size,
                              hipStream_t stream) {
    const float* adj_time  = (const float*)d_in[0];
    const float* gc        = (const float*)d_in[1];
    const float* cur_time  = (const float*)d_in[2];
    const float* neigh_mask= (const float*)d_in[3];
    const float* hist_feat = (const float*)d_in[4];
    const float* hist_time = (const float*)d_in[5];
    const float* t2v_w     = (const float*)d_in[6];
    const float* t2v_b     = (const float*)d_in[7];
    const float* node_w    = (const float*)d_in[8];
    const float* node_b    = (const float*)d_in[9];
    const float* att_w     = (const float*)d_in[10];
    const float* att_b     = (const float*)d_in[11];
    const float* weight    = (const float*)d_in[12];
    const int*   targets   = (const int*)d_in[13];
    const int*   neigh_idx = (const int*)d_in[14];

    float* out   = (float*)d_out;
    float* feat4 = (float*)d_ws;   // B*256 floats = 4 MB

    k1_encode<<<BB, 256, 0, stream>>>(adj_time, gc, cur_time, neigh_mask,
                                      hist_feat, hist_time, t2v_w, t2v_b,
                                      node_w, node_b, att_w, att_b,
                                      targets, neigh_idx, feat4);

    k2_gemm<<<BB / 8, 256, 0, stream>>>(feat4, weight, out);
}